// Round 10
// baseline (583.138 us; speedup 1.0000x reference)
//
#include <hip/hip_runtime.h>
#include <math.h>

#define N_NODES 50000
#define N_EDGES 800000
#define DCH 128
#define N_LAYERS 9
#define N_GRAPHS 256
#define EPSF 1e-5f
#define NCHUNK 196      // ceil(50000/256)
#define NSLICE16 16     // partition slices; slice s -> XCD s%8 (blockIdx%8 round-robin)
#define SL16 3125       // N_NODES / 16; per-slice pass-B working set ~2.4MB < 4MB XCD-L2
#define BUCKET_CAP 131072  // records/slice; max slice load ~74k (top in-degree slice), 1.8x margin

typedef __attribute__((ext_vector_type(8))) short short8;   // 8 bf16 = 4 VGPRs
typedef __attribute__((ext_vector_type(4))) float floatx4;

static __device__ __forceinline__ unsigned short f2bf(float f) {
    unsigned int u = __float_as_uint(f);
    unsigned int r = (u + 0x7fffu + ((u >> 16) & 1u)) >> 16;  // RNE
    return (unsigned short)r;
}
static __device__ __forceinline__ unsigned int pack_bf2(float a, float b) {
    return (unsigned int)f2bf(a) | ((unsigned int)f2bf(b) << 16);
}
static __device__ __forceinline__ float bflo(unsigned int u) { return __uint_as_float(u << 16); }
static __device__ __forceinline__ float bfhi(unsigned int u) { return __uint_as_float(u & 0xffff0000u); }

// D = lo(a)*lo(b) + hi(a)*hi(b) + c   (single VOP3P instruction, full rate)
static __device__ __forceinline__ float dot2bf(unsigned int a, unsigned int b, float c) {
    float d;
    asm("v_dot2_f32_bf16 %0, %1, %2, %3" : "=v"(d) : "v"(a), "v"(b), "v"(c));
    return d;
}

// descending-degree bucket (heavy nodes get low p -> dispatched first, LPT)
static __device__ __forceinline__ int dbucket(int d) { return 63 - min(d, 63); }

// ---------------- degree histogram (original node space) ----------------
__global__ void hist_kernel(const int* __restrict__ dst, int* __restrict__ deg) {
    int t = blockIdx.x * 256 + threadIdx.x;   // grid covers exactly N_EDGES
    atomicAdd(&deg[dst[t]], 1);
}

// ---------------- descending counting sort, two-level (no global hotspots) ----------------
__global__ __launch_bounds__(256) void dsort_hist_kernel(const int* __restrict__ deg,
                                                         int* __restrict__ bhist) {
    __shared__ int lh[64];
    int t = threadIdx.x;
    if (t < 64) lh[t] = 0;
    __syncthreads();
    int n = blockIdx.x * 256 + t;
    if (n < N_NODES) atomicAdd(&lh[dbucket(deg[n])], 1);
    __syncthreads();
    if (t < 64) bhist[blockIdx.x * 64 + t] = lh[t];
}

__global__ __launch_bounds__(64) void dsort_scan_kernel(const int* __restrict__ bhist,
                                                        int* __restrict__ boff) {
    __shared__ int tot[64];
    __shared__ int base[64];
    int b = threadIdx.x;  // thread b owns bucket b
    int s = 0;
    for (int blk = 0; blk < NCHUNK; blk++) s += bhist[blk * 64 + b];
    tot[b] = s;
    __syncthreads();
    if (b == 0) {
        int run = 0;
        for (int i = 0; i < 64; i++) { base[i] = run; run += tot[i]; }
    }
    __syncthreads();
    int run = base[b];
    for (int blk = 0; blk < NCHUNK; blk++) {
        boff[blk * 64 + b] = run;
        run += bhist[blk * 64 + b];
    }
}

__global__ __launch_bounds__(256) void dsort_scatter_kernel(const int* __restrict__ deg,
                                                            const int* __restrict__ boff,
                                                            int* __restrict__ nperm,
                                                            int* __restrict__ inv) {
    __shared__ int cur[64];
    int t = threadIdx.x;
    if (t < 64) cur[t] = boff[blockIdx.x * 64 + t];
    __syncthreads();
    int n = blockIdx.x * 256 + t;
    if (n < N_NODES) {
        int p = atomicAdd(&cur[dbucket(deg[n])], 1);  // LDS atomic, intra-block only
        nperm[p] = n;
        inv[n] = p;
    }
}

// ---------------- CSR build in p-space ----------------
__global__ __launch_bounds__(256) void chunksum_kernel(const int* __restrict__ deg,
                                                       const int* __restrict__ nperm,
                                                       int* __restrict__ csum) {
    int t = threadIdx.x;
    int i = blockIdx.x * 256 + t;
    int v = (i < N_NODES) ? deg[nperm[i]] : 0;
    __shared__ int sh[4];
    for (int off = 32; off >= 1; off >>= 1) v += __shfl_down(v, off);
    if ((t & 63) == 0) sh[t >> 6] = v;
    __syncthreads();
    if (t == 0) csum[blockIdx.x] = sh[0] + sh[1] + sh[2] + sh[3];
}

__global__ __launch_bounds__(256) void chunkscan_kernel(const int* __restrict__ csum,
                                                        int* __restrict__ coff) {
    __shared__ int sh[256];
    int t = threadIdx.x;
    sh[t] = (t < NCHUNK) ? csum[t] : 0;
    __syncthreads();
    for (int off = 1; off < 256; off <<= 1) {
        int v = (t >= off) ? sh[t - off] : 0;
        __syncthreads();
        sh[t] += v;
        __syncthreads();
    }
    if (t < NCHUNK) coff[t] = t ? sh[t - 1] : 0;  // exclusive
}

__global__ __launch_bounds__(256) void applyscan_kernel(const int* __restrict__ deg,
                                                        const int* __restrict__ nperm,
                                                        const int* __restrict__ coff,
                                                        int* __restrict__ rowp,
                                                        int* __restrict__ cursor) {
    __shared__ int sh[256];
    int t = threadIdx.x;
    int i = blockIdx.x * 256 + t;
    int d = (i < N_NODES) ? deg[nperm[i]] : 0;
    sh[t] = d;
    __syncthreads();
    for (int off = 1; off < 256; off <<= 1) {
        int v = (t >= off) ? sh[t - off] : 0;
        __syncthreads();
        sh[t] += v;
        __syncthreads();
    }
    int excl = coff[blockIdx.x] + (t ? sh[t - 1] : 0);
    if (i < N_NODES) {
        rowp[i] = excl;
        cursor[i] = excl;
    }
    if (i == N_NODES - 1) rowp[N_NODES] = N_EDGES;
}

// ---------------- Pass A: dense edge partition into 16 per-slice buckets ----------------
// One streaming pass (round-9 lesson: the 8x slice re-stream of eattr/src churned
// L2 and evicted dirty partial erec lines -> 4x write amplification). Records are
// written DENSELY per slice (block reserves contiguous span via 16 global atomics)
// -> full-line write coverage. inv[] is 200KB, L2-resident -> the per-edge
// inv[dst]/inv[src] gathers are cheap; dstinv precompute kernel eliminated.
__global__ __launch_bounds__(256) void partition_kernel(const int* __restrict__ src,
                                                        const int* __restrict__ dst,
                                                        const int* __restrict__ inv,
                                                        const float* __restrict__ eattr,
                                                        int* __restrict__ tails,
                                                        uint4* __restrict__ buckets) {
    __shared__ int cnt[NSLICE16];
    __shared__ int base[NSLICE16];
    int t = threadIdx.x;
    if (t < NSLICE16) cnt[t] = 0;
    __syncthreads();
    int e0 = blockIdx.x * 1024 + t * 4;
    uint4 rec[4];
    int sl[4], slot[4];
    int nv = 0;
#pragma unroll
    for (int k = 0; k < 4; k++) {
        int e = e0 + k;
        if (e < N_EDGES) {
            int d = inv[dst[e]];
            int s = inv[src[e]];
            float4 a = ((const float4*)eattr)[e];
            int sli = d / SL16;  // magic-mul (constant divisor)
            rec[k] = make_uint4((unsigned int)s, pack_bf2(a.x, a.y), pack_bf2(a.z, a.w),
                                (unsigned int)d);
            sl[k] = sli;
            slot[k] = atomicAdd(&cnt[sli], 1);
            nv = k + 1;
        }
    }
    __syncthreads();
    if (t < NSLICE16) base[t] = (cnt[t] > 0) ? atomicAdd(&tails[t], cnt[t]) : 0;
    __syncthreads();
    for (int k = 0; k < nv; k++) {
        buckets[(size_t)sl[k] * BUCKET_CAP + base[sl[k]] + slot[k]] = rec[k];
    }
}

// ---------------- Pass B: per-slice dst-sort (bucket -> CSR erec) ----------------
// Slice s handled by blocks with blockIdx%16 == s -> XCD s%8. All traffic is
// slice-local: dense bucket read (~1.2MB) + cursor scatter into the slice's
// contiguous erec region (~1.2MB) + cursor (12.5KB) -- fits one XCD L2, so
// dirty erec lines accumulate in L2 and write back ONCE (full lines).
__global__ __launch_bounds__(256) void bucket_kernel(const int* __restrict__ tails,
                                                     const uint4* __restrict__ buckets,
                                                     int* __restrict__ cursor,
                                                     uint4* __restrict__ erec) {
    int s = blockIdx.x & (NSLICE16 - 1);
    int j = blockIdx.x >> 4;
    int tl = tails[s];
    int r0 = j * 1024 + threadIdx.x * 4;
    if (r0 >= tl) return;
    const uint4* bk = buckets + (size_t)s * BUCKET_CAP;
#pragma unroll
    for (int k = 0; k < 4; k++) {
        int r = r0 + k;
        if (r < tl) {
            uint4 rec = bk[r];
            int d = (int)rec.w;
            int p = atomicAdd(&cursor[d], 1);
            erec[p] = rec;  // .w unused by layer
        }
    }
}

// ---------------- conv weights -> MFMA B-fragment layout, bf16 ----------------
__global__ __launch_bounds__(256) void wconv_kernel(const float* __restrict__ convW,
                                                    uint4* __restrict__ wb) {
    int tid = blockIdx.x * 256 + threadIdx.x;  // 72 blocks * 256 = 18432 exactly
    int lane = tid & 63;
    int t = (tid >> 6) & 31;
    int layer = tid >> 11;
    int jt = t >> 2, kt = t & 3;
    int quad = lane >> 4, col = lane & 15;
    const float* Wl = convW + (size_t)layer * DCH * DCH;
    int kbase = kt * 32 + quad * 8;
    int ch = jt * 16 + col;
    unsigned int d0 = pack_bf2(Wl[(kbase + 0) * DCH + ch], Wl[(kbase + 1) * DCH + ch]);
    unsigned int d1 = pack_bf2(Wl[(kbase + 2) * DCH + ch], Wl[(kbase + 3) * DCH + ch]);
    unsigned int d2 = pack_bf2(Wl[(kbase + 4) * DCH + ch], Wl[(kbase + 5) * DCH + ch]);
    unsigned int d3 = pack_bf2(Wl[(kbase + 6) * DCH + ch], Wl[(kbase + 7) * DCH + ch]);
    wb[tid] = make_uint4(d0, d1, d2, d3);
}

// ---------------- h0 = x @ Wv, bf16-packed, written to p-space rows ----------------
__global__ void h0_kernel(const float* __restrict__ x, const float* __restrict__ Wv,
                          const int* __restrict__ inv,
                          unsigned int* __restrict__ hbf) {
    int t = blockIdx.x * 256 + threadIdx.x;
    int n = t >> 6, l = t & 63;
    const float* xr = x + n * 13;
    float s0 = 0.f, s1 = 0.f;
#pragma unroll
    for (int j = 0; j < 13; j++) {
        float xv = xr[j];
        s0 = fmaf(xv, Wv[j * 128 + 2 * l], s0);
        s1 = fmaf(xv, Wv[j * 128 + 2 * l + 1], s1);
    }
    int p = inv[n];  // wave-uniform
    hbf[(size_t)p * 64 + l] = pack_bf2(s0, s1);
}

// ---------------- fused layer (p-space): aggregation + MFMA GEMM + epilogue ----------------
// Round-9 structure (best verified): bf16-only h carry, uint4 erec,
// 2 edges/node/iteration, 8 gather chains in flight, branch-free body.
#define VSTRIDE 68  // node row stride in uints (64 + 4 pad)
#define OLP 132     // epilogue row: 128 + 4
__global__ __launch_bounds__(256) void layer_kernel(const unsigned int* __restrict__ hbfA,
                                                    const uint4* __restrict__ erec,
                                                    const int* __restrict__ rowp,
                                                    const float* __restrict__ We,
                                                    const short8* __restrict__ wbL,
                                                    const float* __restrict__ b,
                                                    unsigned int* __restrict__ hbfB) {
    __shared__ unsigned int vsh[16 * VSTRIDE];  // 4.25 KiB
    __shared__ float ol[16 * OLP];              // 8.25 KiB
    __shared__ unsigned int hsh[16 * 64];       // 4 KiB (bf16 hn carry)
    int tid = threadIdx.x;
    int lane = tid & 63;
    int wave = tid >> 6;
    int nb = blockIdx.x * 16;  // 3125 blocks * 16 = 50000 exactly
    // We packed as bf16 pairs, dot2 operand layout:
    //   wy* pairs with erec.y = (attr0, attr1); wz* pairs with erec.z = (attr2, attr3)
    unsigned int wy0 = pack_bf2(We[0 * 128 + 2 * lane], We[1 * 128 + 2 * lane]);
    unsigned int wz0 = pack_bf2(We[2 * 128 + 2 * lane], We[3 * 128 + 2 * lane]);
    unsigned int wy1 = pack_bf2(We[0 * 128 + 2 * lane + 1], We[1 * 128 + 2 * lane + 1]);
    unsigned int wz1 = pack_bf2(We[2 * 128 + 2 * lane + 1], We[3 * 128 + 2 * lane + 1]);

    int n0 = nb + wave * 4;
    // CSR bounds, forced scalar (wave-uniform) -> SALU loop control
    int s0 = __builtin_amdgcn_readfirstlane(rowp[n0]);
    int s1 = __builtin_amdgcn_readfirstlane(rowp[n0 + 1]);
    int s2 = __builtin_amdgcn_readfirstlane(rowp[n0 + 2]);
    int s3 = __builtin_amdgcn_readfirstlane(rowp[n0 + 3]);
    int s4 = __builtin_amdgcn_readfirstlane(rowp[n0 + 4]);
    int d0 = s1 - s0, d1 = s2 - s1, d2 = s3 - s2, d3 = s4 - s3;
    int dm0 = d0 - 1, dm1 = d1 - 1, dm2 = d2 - 1, dm3 = d3 - 1;
    int maxd = max(max(d0, d1), max(d2, d3));
    int mm = maxd - 1;

    // preload bf16 h carry for the 4 nodes; stash in LDS for the epilogue
    unsigned int hn0 = hbfA[(size_t)(n0 + 0) * 64 + lane];
    unsigned int hn1 = hbfA[(size_t)(n0 + 1) * 64 + lane];
    unsigned int hn2 = hbfA[(size_t)(n0 + 2) * 64 + lane];
    unsigned int hn3 = hbfA[(size_t)(n0 + 3) * 64 + lane];
    hsh[(wave * 4 + 0) * 64 + lane] = hn0;
    hsh[(wave * 4 + 1) * 64 + lane] = hn1;
    hsh[(wave * 4 + 2) * 64 + lane] = hn2;
    hsh[(wave * 4 + 3) * 64 + lane] = hn3;

    float c0x = 0.f, c0y = 0.f, c1x = 0.f, c1y = 0.f;
    float c2x = 0.f, c2y = 0.f, c3x = 0.f, c3y = 0.f;

    if (maxd > 0) {
        // clamped record index: erec[s_j + min(i, dm_j)]; masked when i >= d_j.
        // p-space is descending-degree sorted, so d_j == 0 within an active
        // group implies s_j >= 1 -> the s_j - 1 read is in bounds.
        uint4 qa0 = erec[s0 + min(0, dm0)];
        uint4 qa1 = erec[s1 + min(0, dm1)];
        uint4 qa2 = erec[s2 + min(0, dm2)];
        uint4 qa3 = erec[s3 + min(0, dm3)];
        int i1 = min(1, mm);
        uint4 qb0 = erec[s0 + min(i1, dm0)];
        uint4 qb1 = erec[s1 + min(i1, dm1)];
        uint4 qb2 = erec[s2 + min(i1, dm2)];
        uint4 qb3 = erec[s3 + min(i1, dm3)];
        for (int i = 0; i < maxd; i += 2) {
            // issue 8 gathers (records arrived during previous iteration)
            unsigned int ua0 = hbfA[qa0.x * 64u + (unsigned)lane];
            unsigned int ua1 = hbfA[qa1.x * 64u + (unsigned)lane];
            unsigned int ua2 = hbfA[qa2.x * 64u + (unsigned)lane];
            unsigned int ua3 = hbfA[qa3.x * 64u + (unsigned)lane];
            unsigned int ub0 = hbfA[qb0.x * 64u + (unsigned)lane];
            unsigned int ub1 = hbfA[qb1.x * 64u + (unsigned)lane];
            unsigned int ub2 = hbfA[qb2.x * 64u + (unsigned)lane];
            unsigned int ub3 = hbfA[qb3.x * 64u + (unsigned)lane];
            // save attrs (SSA renames; frees q regs for the prefetch)
            unsigned int ya0 = qa0.y, za0 = qa0.z, ya1 = qa1.y, za1 = qa1.z;
            unsigned int ya2 = qa2.y, za2 = qa2.z, ya3 = qa3.y, za3 = qa3.z;
            unsigned int yb0 = qb0.y, zb0 = qb0.z, yb1 = qb1.y, zb1 = qb1.z;
            unsigned int yb2 = qb2.y, zb2 = qb2.z, yb3 = qb3.y, zb3 = qb3.z;
            // prefetch records for edges i+2, i+3 (clamped) while gathers fly
            int i2 = min(i + 2, mm);
            int i3 = min(i + 3, mm);
            qa0 = erec[s0 + min(i2, dm0)];
            qa1 = erec[s1 + min(i2, dm1)];
            qa2 = erec[s2 + min(i2, dm2)];
            qa3 = erec[s3 + min(i2, dm3)];
            qb0 = erec[s0 + min(i3, dm0)];
            qb1 = erec[s1 + min(i3, dm1)];
            qb2 = erec[s2 + min(i3, dm2)];
            qb3 = erec[s3 + min(i3, dm3)];
            // compute edge i (mask i < d_j) and edge i+1 (mask i+1 < d_j)
            float ma00 = dot2bf(ya0, wy0, dot2bf(za0, wz0, 0.f));
            float ma01 = dot2bf(ya0, wy1, dot2bf(za0, wz1, 0.f));
            float ma10 = dot2bf(ya1, wy0, dot2bf(za1, wz0, 0.f));
            float ma11 = dot2bf(ya1, wy1, dot2bf(za1, wz1, 0.f));
            float ma20 = dot2bf(ya2, wy0, dot2bf(za2, wz0, 0.f));
            float ma21 = dot2bf(ya2, wy1, dot2bf(za2, wz1, 0.f));
            float ma30 = dot2bf(ya3, wy0, dot2bf(za3, wz0, 0.f));
            float ma31 = dot2bf(ya3, wy1, dot2bf(za3, wz1, 0.f));
            c0x += (i < d0) ? fmaxf(bflo(ua0) + ma00, 0.f) : 0.f;
            c0y += (i < d0) ? fmaxf(bfhi(ua0) + ma01, 0.f) : 0.f;
            c1x += (i < d1) ? fmaxf(bflo(ua1) + ma10, 0.f) : 0.f;
            c1y += (i < d1) ? fmaxf(bfhi(ua1) + ma11, 0.f) : 0.f;
            c2x += (i < d2) ? fmaxf(bflo(ua2) + ma20, 0.f) : 0.f;
            c2y += (i < d2) ? fmaxf(bfhi(ua2) + ma21, 0.f) : 0.f;
            c3x += (i < d3) ? fmaxf(bflo(ua3) + ma30, 0.f) : 0.f;
            c3y += (i < d3) ? fmaxf(bfhi(ua3) + ma31, 0.f) : 0.f;
            float mb00 = dot2bf(yb0, wy0, dot2bf(zb0, wz0, 0.f));
            float mb01 = dot2bf(yb0, wy1, dot2bf(zb0, wz1, 0.f));
            float mb10 = dot2bf(yb1, wy0, dot2bf(zb1, wz0, 0.f));
            float mb11 = dot2bf(yb1, wy1, dot2bf(zb1, wz1, 0.f));
            float mb20 = dot2bf(yb2, wy0, dot2bf(zb2, wz0, 0.f));
            float mb21 = dot2bf(yb2, wy1, dot2bf(zb2, wz1, 0.f));
            float mb30 = dot2bf(yb3, wy0, dot2bf(zb3, wz0, 0.f));
            float mb31 = dot2bf(yb3, wy1, dot2bf(zb3, wz1, 0.f));
            int ip = i + 1;
            c0x += (ip < d0) ? fmaxf(bflo(ub0) + mb00, 0.f) : 0.f;
            c0y += (ip < d0) ? fmaxf(bfhi(ub0) + mb01, 0.f) : 0.f;
            c1x += (ip < d1) ? fmaxf(bflo(ub1) + mb10, 0.f) : 0.f;
            c1y += (ip < d1) ? fmaxf(bfhi(ub1) + mb11, 0.f) : 0.f;
            c2x += (ip < d2) ? fmaxf(bflo(ub2) + mb20, 0.f) : 0.f;
            c2y += (ip < d2) ? fmaxf(bfhi(ub2) + mb21, 0.f) : 0.f;
            c3x += (ip < d3) ? fmaxf(bflo(ub3) + mb30, 0.f) : 0.f;
            c3y += (ip < d3) ? fmaxf(bfhi(ub3) + mb31, 0.f) : 0.f;
        }
    }
    // flush all 4 nodes: v = (1+eps)*h + aggr, packed bf16
    vsh[(wave * 4 + 0) * VSTRIDE + lane] =
        pack_bf2(fmaf(bflo(hn0), 1.f + EPSF, c0x), fmaf(bfhi(hn0), 1.f + EPSF, c0y));
    vsh[(wave * 4 + 1) * VSTRIDE + lane] =
        pack_bf2(fmaf(bflo(hn1), 1.f + EPSF, c1x), fmaf(bfhi(hn1), 1.f + EPSF, c1y));
    vsh[(wave * 4 + 2) * VSTRIDE + lane] =
        pack_bf2(fmaf(bflo(hn2), 1.f + EPSF, c2x), fmaf(bfhi(hn2), 1.f + EPSF, c2y));
    vsh[(wave * 4 + 3) * VSTRIDE + lane] =
        pack_bf2(fmaf(bflo(hn3), 1.f + EPSF, c3x), fmaf(bfhi(hn3), 1.f + EPSF, c3y));

    __syncthreads();
    // ---- MFMA: shared 16-node A, each wave does jt = 2*wave, 2*wave+1 ----
    int col = lane & 15, quad = lane >> 4;
    short8 a[4];
#pragma unroll
    for (int kt = 0; kt < 4; kt++) {
        a[kt] = *(const short8*)(vsh + col * VSTRIDE + kt * 16 + quad * 4);
    }
#pragma unroll
    for (int jj = 0; jj < 2; jj++) {
        int jt = wave * 2 + jj;
        floatx4 acc = {0.f, 0.f, 0.f, 0.f};
#pragma unroll
        for (int kt = 0; kt < 4; kt++) {
            short8 bf = wbL[(jt * 4 + kt) * 64 + lane];
            acc = __builtin_amdgcn_mfma_f32_16x16x32_bf16(a[kt], bf, acc, 0, 0, 0);
        }
        float bv = b[jt * 16 + col];
#pragma unroll
        for (int r = 0; r < 4; r++) {
            ol[(quad * 4 + r) * OLP + jt * 16 + col] = fmaxf(acc[r] + bv, 0.f);
        }
    }
    __syncthreads();
    // ---- coalesced epilogue: 16 nodes x 32 chunks of 4 channels = 512 items ----
    uint2* b2v = (uint2*)hbfB;
#pragma unroll
    for (int i = 0; i < 2; i++) {
        int idx = i * 256 + tid;            // 0..511
        int nl2 = idx >> 5, c4 = idx & 31;
        int node = nb + nl2;
        const float* row = ol + nl2 * OLP + c4 * 4;
        unsigned int h01 = hsh[nl2 * 64 + 2 * c4];
        unsigned int h23 = hsh[nl2 * 64 + 2 * c4 + 1];
        float r0 = row[0] + bflo(h01);
        float r1 = row[1] + bfhi(h01);
        float r2 = row[2] + bflo(h23);
        float r3 = row[3] + bfhi(h23);
        b2v[(size_t)node * 32 + c4] = make_uint2(pack_bf2(r0, r1), pack_bf2(r2, r3));
    }
}

// ---------------- graph boundaries (batch is sorted) ----------------
__global__ void bounds_kernel(const int* __restrict__ batch, int* __restrict__ gs) {
    int n = blockIdx.x * 256 + threadIdx.x;
    if (n >= N_NODES) return;
    int bcur = batch[n];
    int prev = (n == 0) ? -1 : batch[n - 1];
    for (int g = prev + 1; g <= bcur; g++) gs[g] = n;
    if (n == N_NODES - 1) {
        for (int g = bcur + 1; g <= N_GRAPHS; g++) gs[g] = N_NODES;
    }
}

// ---------------- sum pool: orig-node order (batch sorted), bf16 h rows via inv ----------------
__global__ __launch_bounds__(256) void pool_kernel(const unsigned int* __restrict__ hbf,
                                                   const int* __restrict__ inv,
                                                   const int* __restrict__ batch,
                                                   float* __restrict__ sums) {
    int wave = threadIdx.x >> 6, l = threadIdx.x & 63;
    int nbase = (blockIdx.x * 4 + wave) * 8;
    float a0 = 0.f, a1 = 0.f;
    int g = -1;
#pragma unroll
    for (int i = 0; i < 8; i++) {
        int n = nbase + i;
        if (n >= N_NODES) break;
        int bg = batch[n];
        if (bg != g) {
            if (g >= 0) {
                atomicAdd(&sums[g * 128 + 2 * l], a0);
                atomicAdd(&sums[g * 128 + 2 * l + 1], a1);
            }
            g = bg; a0 = 0.f; a1 = 0.f;
        }
        int p = inv[n];  // wave-uniform
        unsigned int hv = hbf[(size_t)p * 64 + l];
        a0 += bflo(hv); a1 += bfhi(hv);
    }
    if (g >= 0) {
        atomicAdd(&sums[g * 128 + 2 * l], a0);
        atomicAdd(&sums[g * 128 + 2 * l + 1], a1);
    }
}

// ---------------- MLP head (divides pooled sums by count inline) ----------------
__global__ __launch_bounds__(512) void mlp_kernel(const float* __restrict__ sums,
                                                  const int* __restrict__ gs,
                                                  const float* __restrict__ Wh1,
                                                  const float* __restrict__ bh1,
                                                  const float* __restrict__ Wh2,
                                                  const float* __restrict__ bh2,
                                                  float* __restrict__ out) {
    int g = blockIdx.x;
    __shared__ float pl[128];
    __shared__ float red[8];
    int tid = threadIdx.x;
    if (tid < 128) {
        float cnt = fmaxf((float)(gs[g + 1] - gs[g]), 1.0f);
        pl[tid] = sums[g * 128 + tid] / cnt;
    }
    __syncthreads();
    float s = bh1[tid];
#pragma unroll 16
    for (int k = 0; k < 128; k++) s = fmaf(pl[k], Wh1[k * 512 + tid], s);
    float gl = 0.5f * s * (1.0f + erff(s * 0.70710678118654752f));
    float p = gl * Wh2[tid];
    for (int off = 32; off >= 1; off >>= 1) p += __shfl_down(p, off);
    if ((tid & 63) == 0) red[tid >> 6] = p;
    __syncthreads();
    if (tid == 0) {
        float tot = 0.f;
        for (int i = 0; i < 8; i++) tot += red[i];
        out[g] = tot + bh2[0];
    }
}

extern "C" void kernel_launch(void* const* d_in, const int* in_sizes, int n_in,
                              void* d_out, int out_size, void* d_ws, size_t ws_size,
                              hipStream_t stream) {
    const float* x = (const float*)d_in[0];
    const int* ei = (const int*)d_in[1];
    const float* eattr = (const float*)d_in[2];
    const int* batch = (const int*)d_in[3];
    const float* Wv = (const float*)d_in[4];
    const float* We = (const float*)d_in[5];
    const float* convW = (const float*)d_in[6];
    const float* convB = (const float*)d_in[7];
    const float* Wh1 = (const float*)d_in[8];
    const float* bh1 = (const float*)d_in[9];
    const float* Wh2 = (const float*)d_in[10];
    const float* bh2 = (const float*)d_in[11];
    float* out = (float*)d_out;

    const int* src = ei;
    const int* dst = ei + N_EDGES;

    // workspace carve-up (256B aligned) — total ~75 MB
    char* w = (char*)d_ws;
    size_t off = 0;
    auto alloc = [&](size_t bytes) -> char* {
        char* p = w + off;
        off += (bytes + 255) & ~(size_t)255;
        return p;
    };
    unsigned int* hbfA = (unsigned int*)alloc((size_t)N_NODES * 64 * 4);  // bf16 h ping
    unsigned int* hbfB = (unsigned int*)alloc((size_t)N_NODES * 64 * 4);  // bf16 h pong
    uint4* wb = (uint4*)alloc((size_t)N_LAYERS * 32 * 64 * 16);           // MFMA W frags
    int* deg = (int*)alloc((size_t)(N_NODES + 1) * 4);
    int* rowp = (int*)alloc((size_t)(N_NODES + 1) * 4);
    int* cursor = (int*)alloc((size_t)(N_NODES + 1) * 4);
    int* csum = (int*)alloc((size_t)NCHUNK * 4);
    int* coff = (int*)alloc((size_t)NCHUNK * 4);
    int* bhist = (int*)alloc((size_t)NCHUNK * 64 * 4);
    int* boff = (int*)alloc((size_t)NCHUNK * 64 * 4);
    int* nperm = (int*)alloc((size_t)N_NODES * 4);
    int* inv = (int*)alloc((size_t)N_NODES * 4);
    int* tails = (int*)alloc((size_t)NSLICE16 * 4);
    uint4* buckets = (uint4*)alloc((size_t)NSLICE16 * BUCKET_CAP * 16);   // 32 MB
    uint4* erec = (uint4*)alloc((size_t)N_EDGES * 16);
    int* gs = (int*)alloc((size_t)(N_GRAPHS + 1) * 4);
    float* sums = (float*)alloc((size_t)N_GRAPHS * DCH * 4);
    (void)ws_size; (void)n_in; (void)in_sizes; (void)out_size;

    hipMemsetAsync(deg, 0, (size_t)(N_NODES + 1) * 4, stream);
    hipMemsetAsync(tails, 0, (size_t)NSLICE16 * 4, stream);
    hipMemsetAsync(sums, 0, (size_t)N_GRAPHS * DCH * 4, stream);

    hist_kernel<<<N_EDGES / 256, 256, 0, stream>>>(dst, deg);
    dsort_hist_kernel<<<NCHUNK, 256, 0, stream>>>(deg, bhist);
    dsort_scan_kernel<<<1, 64, 0, stream>>>(bhist, boff);
    dsort_scatter_kernel<<<NCHUNK, 256, 0, stream>>>(deg, boff, nperm, inv);
    chunksum_kernel<<<NCHUNK, 256, 0, stream>>>(deg, nperm, csum);
    chunkscan_kernel<<<1, 256, 0, stream>>>(csum, coff);
    applyscan_kernel<<<NCHUNK, 256, 0, stream>>>(deg, nperm, coff, rowp, cursor);
    partition_kernel<<<(N_EDGES + 1023) / 1024, 256, 0, stream>>>(src, dst, inv, eattr,
                                                                  tails, buckets);
    bucket_kernel<<<(BUCKET_CAP / 1024) * NSLICE16, 256, 0, stream>>>(tails, buckets,
                                                                      cursor, erec);
    wconv_kernel<<<72, 256, 0, stream>>>(convW, wb);
    h0_kernel<<<N_NODES * 64 / 256, 256, 0, stream>>>(x, Wv, inv, hbfA);
    bounds_kernel<<<(N_NODES + 255) / 256, 256, 0, stream>>>(batch, gs);

    unsigned int* bfcur = hbfA;
    unsigned int* bfnext = hbfB;
    for (int layer = 0; layer < N_LAYERS; layer++) {
        layer_kernel<<<N_NODES / 16, 256, 0, stream>>>(
            bfcur, erec, rowp, We,
            (const short8*)(wb + (size_t)layer * 2048), convB + (size_t)layer * DCH,
            bfnext);
        unsigned int* tb = bfcur; bfcur = bfnext; bfnext = tb;
    }

    pool_kernel<<<(N_NODES + 31) / 32, 256, 0, stream>>>(bfcur, inv, batch, sums);
    mlp_kernel<<<N_GRAPHS, 512, 0, stream>>>(sums, gs, Wh1, bh1, Wh2, bh2, out);
}

// Round 11
// 567.608 us; speedup vs baseline: 1.0274x; 1.0274x over previous
//
#include <hip/hip_runtime.h>
#include <math.h>

#define N_NODES 50000
#define N_EDGES 800000
#define DCH 128
#define N_LAYERS 9
#define N_GRAPHS 256
#define EPSF 1e-5f
#define NCHUNK 196   // ceil(50000/256)
#define NSLICE 8     // slice == blockIdx&7 == XCD residue -> single-XCD erec/cursor ownership
#define SL_SZ 6250   // N_NODES / 8 slices; < 2^13 so (slice<<13)|local fits u16

typedef __attribute__((ext_vector_type(8))) short short8;   // 8 bf16 = 4 VGPRs
typedef __attribute__((ext_vector_type(4))) float floatx4;

static __device__ __forceinline__ unsigned short f2bf(float f) {
    unsigned int u = __float_as_uint(f);
    unsigned int r = (u + 0x7fffu + ((u >> 16) & 1u)) >> 16;  // RNE
    return (unsigned short)r;
}
static __device__ __forceinline__ unsigned int pack_bf2(float a, float b) {
    return (unsigned int)f2bf(a) | ((unsigned int)f2bf(b) << 16);
}
static __device__ __forceinline__ float bflo(unsigned int u) { return __uint_as_float(u << 16); }
static __device__ __forceinline__ float bfhi(unsigned int u) { return __uint_as_float(u & 0xffff0000u); }

// D = lo(a)*lo(b) + hi(a)*hi(b) + c   (single VOP3P instruction, full rate)
static __device__ __forceinline__ float dot2bf(unsigned int a, unsigned int b, float c) {
    float d;
    asm("v_dot2_f32_bf16 %0, %1, %2, %3" : "=v"(d) : "v"(a), "v"(b), "v"(c));
    return d;
}

// descending-degree bucket (heavy nodes get low p -> dispatched first, LPT)
static __device__ __forceinline__ int dbucket(int d) { return 63 - min(d, 63); }

// ---------------- degree histogram (original node space) ----------------
__global__ void hist_kernel(const int* __restrict__ dst, int* __restrict__ deg) {
    int t = blockIdx.x * 256 + threadIdx.x;   // grid covers exactly N_EDGES
    atomicAdd(&deg[dst[t]], 1);
}

// ---------------- descending counting sort, two-level (no global hotspots) ----------------
__global__ __launch_bounds__(256) void dsort_hist_kernel(const int* __restrict__ deg,
                                                         int* __restrict__ bhist) {
    __shared__ int lh[64];
    int t = threadIdx.x;
    if (t < 64) lh[t] = 0;
    __syncthreads();
    int n = blockIdx.x * 256 + t;
    if (n < N_NODES) atomicAdd(&lh[dbucket(deg[n])], 1);
    __syncthreads();
    if (t < 64) bhist[blockIdx.x * 64 + t] = lh[t];
}

__global__ __launch_bounds__(64) void dsort_scan_kernel(const int* __restrict__ bhist,
                                                        int* __restrict__ boff) {
    __shared__ int tot[64];
    __shared__ int base[64];
    int b = threadIdx.x;  // thread b owns bucket b
    int s = 0;
    for (int blk = 0; blk < NCHUNK; blk++) s += bhist[blk * 64 + b];
    tot[b] = s;
    __syncthreads();
    if (b == 0) {
        int run = 0;
        for (int i = 0; i < 64; i++) { base[i] = run; run += tot[i]; }
    }
    __syncthreads();
    int run = base[b];
    for (int blk = 0; blk < NCHUNK; blk++) {
        boff[blk * 64 + b] = run;
        run += bhist[blk * 64 + b];
    }
}

__global__ __launch_bounds__(256) void dsort_scatter_kernel(const int* __restrict__ deg,
                                                            const int* __restrict__ boff,
                                                            int* __restrict__ nperm,
                                                            int* __restrict__ inv) {
    __shared__ int cur[64];
    int t = threadIdx.x;
    if (t < 64) cur[t] = boff[blockIdx.x * 64 + t];
    __syncthreads();
    int n = blockIdx.x * 256 + t;
    if (n < N_NODES) {
        int p = atomicAdd(&cur[dbucket(deg[n])], 1);  // LDS atomic, intra-block only
        nperm[p] = n;
        inv[n] = p;
    }
}

// dstinv16[e] = packed (slice<<13)|local of inv[dst[e]] — halves the 8x
// slice re-read traffic in scatter vs 32-bit dstinv.
__global__ void dstinv_kernel(const int* __restrict__ dst, const int* __restrict__ inv,
                              unsigned short* __restrict__ dstinv16) {
    int t = blockIdx.x * 256 + threadIdx.x;
    int d = inv[dst[t]];
    dstinv16[t] = (unsigned short)(((d / SL_SZ) << 13) | (d % SL_SZ));
}

// ---------------- CSR build in p-space ----------------
__global__ __launch_bounds__(256) void chunksum_kernel(const int* __restrict__ deg,
                                                       const int* __restrict__ nperm,
                                                       int* __restrict__ csum) {
    int t = threadIdx.x;
    int i = blockIdx.x * 256 + t;
    int v = (i < N_NODES) ? deg[nperm[i]] : 0;
    __shared__ int sh[4];
    for (int off = 32; off >= 1; off >>= 1) v += __shfl_down(v, off);
    if ((t & 63) == 0) sh[t >> 6] = v;
    __syncthreads();
    if (t == 0) csum[blockIdx.x] = sh[0] + sh[1] + sh[2] + sh[3];
}

__global__ __launch_bounds__(256) void chunkscan_kernel(const int* __restrict__ csum,
                                                        int* __restrict__ coff) {
    __shared__ int sh[256];
    int t = threadIdx.x;
    sh[t] = (t < NCHUNK) ? csum[t] : 0;
    __syncthreads();
    for (int off = 1; off < 256; off <<= 1) {
        int v = (t >= off) ? sh[t - off] : 0;
        __syncthreads();
        sh[t] += v;
        __syncthreads();
    }
    if (t < NCHUNK) coff[t] = t ? sh[t - 1] : 0;  // exclusive
}

__global__ __launch_bounds__(256) void applyscan_kernel(const int* __restrict__ deg,
                                                        const int* __restrict__ nperm,
                                                        const int* __restrict__ coff,
                                                        int* __restrict__ rowp,
                                                        int* __restrict__ cursor) {
    __shared__ int sh[256];
    int t = threadIdx.x;
    int i = blockIdx.x * 256 + t;
    int d = (i < N_NODES) ? deg[nperm[i]] : 0;
    sh[t] = d;
    __syncthreads();
    for (int off = 1; off < 256; off <<= 1) {
        int v = (t >= off) ? sh[t - off] : 0;
        __syncthreads();
        sh[t] += v;
        __syncthreads();
    }
    int excl = coff[blockIdx.x] + (t ? sh[t - 1] : 0);
    if (i < N_NODES) {
        rowp[i] = excl;
        cursor[i] = excl;
    }
    if (i == N_NODES - 1) rowp[N_NODES] = N_EDGES;
}

// Sliced scatter in p-space: block (chunk, s) keeps edges whose p-space dst is
// in slice s; slice == blockIdx&7 == XCD residue. Packed u16 dstinv: slice
// test is a shift-compare, and the 8x re-read costs half the bytes.
// NO nontemporal loads anywhere (rounds 5+8: every stream here is effectively
// multi-read across slice passes; NT refetches regress FETCH). Round-10 lesson:
// the two-pass dense-bucket variant is net slower (extra full pass > write-amp
// savings; per-XCD working set 2 slices x 2.4MB > 4MB L2).
__global__ __launch_bounds__(256) void scatter_kernel(const int* __restrict__ src,
                                                      const unsigned short* __restrict__ dstinv16,
                                                      const int* __restrict__ inv,
                                                      const float* __restrict__ eattr,
                                                      int* __restrict__ cursor,
                                                      uint4* __restrict__ erec) {
    int s = blockIdx.x & (NSLICE - 1);
    int chunk = blockIdx.x / NSLICE;
    int e0 = chunk * 1024 + threadIdx.x * 4;
    if (e0 >= N_EDGES) return;
    ushort4 d4 = *(const ushort4*)(dstinv16 + e0);
#pragma unroll
    for (int k = 0; k < 4; k++) {
        int e = e0 + k;
        unsigned int v = (k == 0) ? d4.x : (k == 1) ? d4.y : (k == 2) ? d4.z : d4.w;
        if ((int)(v >> 13) == s) {
            int d = s * SL_SZ + (int)(v & 0x1FFFu);
            int p = atomicAdd(&cursor[d], 1);
            float4 a = ((const float4*)eattr)[e];
            erec[p] = make_uint4((unsigned int)inv[src[e]],
                                 pack_bf2(a.x, a.y), pack_bf2(a.z, a.w), 0u);
        }
    }
}

// ---------------- conv weights -> MFMA B-fragment layout, bf16 ----------------
__global__ __launch_bounds__(256) void wconv_kernel(const float* __restrict__ convW,
                                                    uint4* __restrict__ wb) {
    int tid = blockIdx.x * 256 + threadIdx.x;  // 72 blocks * 256 = 18432 exactly
    int lane = tid & 63;
    int t = (tid >> 6) & 31;
    int layer = tid >> 11;
    int jt = t >> 2, kt = t & 3;
    int quad = lane >> 4, col = lane & 15;
    const float* Wl = convW + (size_t)layer * DCH * DCH;
    int kbase = kt * 32 + quad * 8;
    int ch = jt * 16 + col;
    unsigned int d0 = pack_bf2(Wl[(kbase + 0) * DCH + ch], Wl[(kbase + 1) * DCH + ch]);
    unsigned int d1 = pack_bf2(Wl[(kbase + 2) * DCH + ch], Wl[(kbase + 3) * DCH + ch]);
    unsigned int d2 = pack_bf2(Wl[(kbase + 4) * DCH + ch], Wl[(kbase + 5) * DCH + ch]);
    unsigned int d3 = pack_bf2(Wl[(kbase + 6) * DCH + ch], Wl[(kbase + 7) * DCH + ch]);
    wb[tid] = make_uint4(d0, d1, d2, d3);
}

// ---------------- h0 = x @ Wv, bf16-packed, written to p-space rows ----------------
__global__ void h0_kernel(const float* __restrict__ x, const float* __restrict__ Wv,
                          const int* __restrict__ inv,
                          unsigned int* __restrict__ hbf) {
    int t = blockIdx.x * 256 + threadIdx.x;
    int n = t >> 6, l = t & 63;
    const float* xr = x + n * 13;
    float s0 = 0.f, s1 = 0.f;
#pragma unroll
    for (int j = 0; j < 13; j++) {
        float xv = xr[j];
        s0 = fmaf(xv, Wv[j * 128 + 2 * l], s0);
        s1 = fmaf(xv, Wv[j * 128 + 2 * l + 1], s1);
    }
    int p = inv[n];  // wave-uniform
    hbf[(size_t)p * 64 + l] = pack_bf2(s0, s1);
}

// ---------------- fused layer (p-space): aggregation + MFMA GEMM + epilogue ----------------
// Best verified structure: bf16-only h carry, uint4 erec,
// 2 edges/node/iteration, 8 gather chains in flight, branch-free body.
#define VSTRIDE 68  // node row stride in uints (64 + 4 pad)
#define OLP 132     // epilogue row: 128 + 4
__global__ __launch_bounds__(256) void layer_kernel(const unsigned int* __restrict__ hbfA,
                                                    const uint4* __restrict__ erec,
                                                    const int* __restrict__ rowp,
                                                    const float* __restrict__ We,
                                                    const short8* __restrict__ wbL,
                                                    const float* __restrict__ b,
                                                    unsigned int* __restrict__ hbfB) {
    __shared__ unsigned int vsh[16 * VSTRIDE];  // 4.25 KiB
    __shared__ float ol[16 * OLP];              // 8.25 KiB
    __shared__ unsigned int hsh[16 * 64];       // 4 KiB (bf16 hn carry)
    int tid = threadIdx.x;
    int lane = tid & 63;
    int wave = tid >> 6;
    int nb = blockIdx.x * 16;  // 3125 blocks * 16 = 50000 exactly
    // We packed as bf16 pairs, dot2 operand layout:
    //   wy* pairs with erec.y = (attr0, attr1); wz* pairs with erec.z = (attr2, attr3)
    unsigned int wy0 = pack_bf2(We[0 * 128 + 2 * lane], We[1 * 128 + 2 * lane]);
    unsigned int wz0 = pack_bf2(We[2 * 128 + 2 * lane], We[3 * 128 + 2 * lane]);
    unsigned int wy1 = pack_bf2(We[0 * 128 + 2 * lane + 1], We[1 * 128 + 2 * lane + 1]);
    unsigned int wz1 = pack_bf2(We[2 * 128 + 2 * lane + 1], We[3 * 128 + 2 * lane + 1]);

    int n0 = nb + wave * 4;
    // CSR bounds, forced scalar (wave-uniform) -> SALU loop control
    int s0 = __builtin_amdgcn_readfirstlane(rowp[n0]);
    int s1 = __builtin_amdgcn_readfirstlane(rowp[n0 + 1]);
    int s2 = __builtin_amdgcn_readfirstlane(rowp[n0 + 2]);
    int s3 = __builtin_amdgcn_readfirstlane(rowp[n0 + 3]);
    int s4 = __builtin_amdgcn_readfirstlane(rowp[n0 + 4]);
    int d0 = s1 - s0, d1 = s2 - s1, d2 = s3 - s2, d3 = s4 - s3;
    int dm0 = d0 - 1, dm1 = d1 - 1, dm2 = d2 - 1, dm3 = d3 - 1;
    int maxd = max(max(d0, d1), max(d2, d3));
    int mm = maxd - 1;

    // preload bf16 h carry for the 4 nodes; stash in LDS for the epilogue
    unsigned int hn0 = hbfA[(size_t)(n0 + 0) * 64 + lane];
    unsigned int hn1 = hbfA[(size_t)(n0 + 1) * 64 + lane];
    unsigned int hn2 = hbfA[(size_t)(n0 + 2) * 64 + lane];
    unsigned int hn3 = hbfA[(size_t)(n0 + 3) * 64 + lane];
    hsh[(wave * 4 + 0) * 64 + lane] = hn0;
    hsh[(wave * 4 + 1) * 64 + lane] = hn1;
    hsh[(wave * 4 + 2) * 64 + lane] = hn2;
    hsh[(wave * 4 + 3) * 64 + lane] = hn3;

    float c0x = 0.f, c0y = 0.f, c1x = 0.f, c1y = 0.f;
    float c2x = 0.f, c2y = 0.f, c3x = 0.f, c3y = 0.f;

    if (maxd > 0) {
        // clamped record index: erec[s_j + min(i, dm_j)]; masked when i >= d_j.
        // p-space is descending-degree sorted, so d_j == 0 within an active
        // group implies s_j >= 1 -> the s_j - 1 read is in bounds.
        uint4 qa0 = erec[s0 + min(0, dm0)];
        uint4 qa1 = erec[s1 + min(0, dm1)];
        uint4 qa2 = erec[s2 + min(0, dm2)];
        uint4 qa3 = erec[s3 + min(0, dm3)];
        int i1 = min(1, mm);
        uint4 qb0 = erec[s0 + min(i1, dm0)];
        uint4 qb1 = erec[s1 + min(i1, dm1)];
        uint4 qb2 = erec[s2 + min(i1, dm2)];
        uint4 qb3 = erec[s3 + min(i1, dm3)];
        for (int i = 0; i < maxd; i += 2) {
            // issue 8 gathers (records arrived during previous iteration)
            unsigned int ua0 = hbfA[qa0.x * 64u + (unsigned)lane];
            unsigned int ua1 = hbfA[qa1.x * 64u + (unsigned)lane];
            unsigned int ua2 = hbfA[qa2.x * 64u + (unsigned)lane];
            unsigned int ua3 = hbfA[qa3.x * 64u + (unsigned)lane];
            unsigned int ub0 = hbfA[qb0.x * 64u + (unsigned)lane];
            unsigned int ub1 = hbfA[qb1.x * 64u + (unsigned)lane];
            unsigned int ub2 = hbfA[qb2.x * 64u + (unsigned)lane];
            unsigned int ub3 = hbfA[qb3.x * 64u + (unsigned)lane];
            // save attrs (SSA renames; frees q regs for the prefetch)
            unsigned int ya0 = qa0.y, za0 = qa0.z, ya1 = qa1.y, za1 = qa1.z;
            unsigned int ya2 = qa2.y, za2 = qa2.z, ya3 = qa3.y, za3 = qa3.z;
            unsigned int yb0 = qb0.y, zb0 = qb0.z, yb1 = qb1.y, zb1 = qb1.z;
            unsigned int yb2 = qb2.y, zb2 = qb2.z, yb3 = qb3.y, zb3 = qb3.z;
            // prefetch records for edges i+2, i+3 (clamped) while gathers fly
            int i2 = min(i + 2, mm);
            int i3 = min(i + 3, mm);
            qa0 = erec[s0 + min(i2, dm0)];
            qa1 = erec[s1 + min(i2, dm1)];
            qa2 = erec[s2 + min(i2, dm2)];
            qa3 = erec[s3 + min(i2, dm3)];
            qb0 = erec[s0 + min(i3, dm0)];
            qb1 = erec[s1 + min(i3, dm1)];
            qb2 = erec[s2 + min(i3, dm2)];
            qb3 = erec[s3 + min(i3, dm3)];
            // compute edge i (mask i < d_j) and edge i+1 (mask i+1 < d_j)
            float ma00 = dot2bf(ya0, wy0, dot2bf(za0, wz0, 0.f));
            float ma01 = dot2bf(ya0, wy1, dot2bf(za0, wz1, 0.f));
            float ma10 = dot2bf(ya1, wy0, dot2bf(za1, wz0, 0.f));
            float ma11 = dot2bf(ya1, wy1, dot2bf(za1, wz1, 0.f));
            float ma20 = dot2bf(ya2, wy0, dot2bf(za2, wz0, 0.f));
            float ma21 = dot2bf(ya2, wy1, dot2bf(za2, wz1, 0.f));
            float ma30 = dot2bf(ya3, wy0, dot2bf(za3, wz0, 0.f));
            float ma31 = dot2bf(ya3, wy1, dot2bf(za3, wz1, 0.f));
            c0x += (i < d0) ? fmaxf(bflo(ua0) + ma00, 0.f) : 0.f;
            c0y += (i < d0) ? fmaxf(bfhi(ua0) + ma01, 0.f) : 0.f;
            c1x += (i < d1) ? fmaxf(bflo(ua1) + ma10, 0.f) : 0.f;
            c1y += (i < d1) ? fmaxf(bfhi(ua1) + ma11, 0.f) : 0.f;
            c2x += (i < d2) ? fmaxf(bflo(ua2) + ma20, 0.f) : 0.f;
            c2y += (i < d2) ? fmaxf(bfhi(ua2) + ma21, 0.f) : 0.f;
            c3x += (i < d3) ? fmaxf(bflo(ua3) + ma30, 0.f) : 0.f;
            c3y += (i < d3) ? fmaxf(bfhi(ua3) + ma31, 0.f) : 0.f;
            float mb00 = dot2bf(yb0, wy0, dot2bf(zb0, wz0, 0.f));
            float mb01 = dot2bf(yb0, wy1, dot2bf(zb0, wz1, 0.f));
            float mb10 = dot2bf(yb1, wy0, dot2bf(zb1, wz0, 0.f));
            float mb11 = dot2bf(yb1, wy1, dot2bf(zb1, wz1, 0.f));
            float mb20 = dot2bf(yb2, wy0, dot2bf(zb2, wz0, 0.f));
            float mb21 = dot2bf(yb2, wy1, dot2bf(zb2, wz1, 0.f));
            float mb30 = dot2bf(yb3, wy0, dot2bf(zb3, wz0, 0.f));
            float mb31 = dot2bf(yb3, wy1, dot2bf(zb3, wz1, 0.f));
            int ip = i + 1;
            c0x += (ip < d0) ? fmaxf(bflo(ub0) + mb00, 0.f) : 0.f;
            c0y += (ip < d0) ? fmaxf(bfhi(ub0) + mb01, 0.f) : 0.f;
            c1x += (ip < d1) ? fmaxf(bflo(ub1) + mb10, 0.f) : 0.f;
            c1y += (ip < d1) ? fmaxf(bfhi(ub1) + mb11, 0.f) : 0.f;
            c2x += (ip < d2) ? fmaxf(bflo(ub2) + mb20, 0.f) : 0.f;
            c2y += (ip < d2) ? fmaxf(bfhi(ub2) + mb21, 0.f) : 0.f;
            c3x += (ip < d3) ? fmaxf(bflo(ub3) + mb30, 0.f) : 0.f;
            c3y += (ip < d3) ? fmaxf(bfhi(ub3) + mb31, 0.f) : 0.f;
        }
    }
    // flush all 4 nodes: v = (1+eps)*h + aggr, packed bf16
    vsh[(wave * 4 + 0) * VSTRIDE + lane] =
        pack_bf2(fmaf(bflo(hn0), 1.f + EPSF, c0x), fmaf(bfhi(hn0), 1.f + EPSF, c0y));
    vsh[(wave * 4 + 1) * VSTRIDE + lane] =
        pack_bf2(fmaf(bflo(hn1), 1.f + EPSF, c1x), fmaf(bfhi(hn1), 1.f + EPSF, c1y));
    vsh[(wave * 4 + 2) * VSTRIDE + lane] =
        pack_bf2(fmaf(bflo(hn2), 1.f + EPSF, c2x), fmaf(bfhi(hn2), 1.f + EPSF, c2y));
    vsh[(wave * 4 + 3) * VSTRIDE + lane] =
        pack_bf2(fmaf(bflo(hn3), 1.f + EPSF, c3x), fmaf(bfhi(hn3), 1.f + EPSF, c3y));

    __syncthreads();
    // ---- MFMA: shared 16-node A, each wave does jt = 2*wave, 2*wave+1 ----
    int col = lane & 15, quad = lane >> 4;
    short8 a[4];
#pragma unroll
    for (int kt = 0; kt < 4; kt++) {
        a[kt] = *(const short8*)(vsh + col * VSTRIDE + kt * 16 + quad * 4);
    }
#pragma unroll
    for (int jj = 0; jj < 2; jj++) {
        int jt = wave * 2 + jj;
        floatx4 acc = {0.f, 0.f, 0.f, 0.f};
#pragma unroll
        for (int kt = 0; kt < 4; kt++) {
            short8 bf = wbL[(jt * 4 + kt) * 64 + lane];
            acc = __builtin_amdgcn_mfma_f32_16x16x32_bf16(a[kt], bf, acc, 0, 0, 0);
        }
        float bv = b[jt * 16 + col];
#pragma unroll
        for (int r = 0; r < 4; r++) {
            ol[(quad * 4 + r) * OLP + jt * 16 + col] = fmaxf(acc[r] + bv, 0.f);
        }
    }
    __syncthreads();
    // ---- coalesced epilogue: 16 nodes x 32 chunks of 4 channels = 512 items ----
    uint2* b2v = (uint2*)hbfB;
#pragma unroll
    for (int i = 0; i < 2; i++) {
        int idx = i * 256 + tid;            // 0..511
        int nl2 = idx >> 5, c4 = idx & 31;
        int node = nb + nl2;
        const float* row = ol + nl2 * OLP + c4 * 4;
        unsigned int h01 = hsh[nl2 * 64 + 2 * c4];
        unsigned int h23 = hsh[nl2 * 64 + 2 * c4 + 1];
        float r0 = row[0] + bflo(h01);
        float r1 = row[1] + bfhi(h01);
        float r2 = row[2] + bflo(h23);
        float r3 = row[3] + bfhi(h23);
        b2v[(size_t)node * 32 + c4] = make_uint2(pack_bf2(r0, r1), pack_bf2(r2, r3));
    }
}

// ---------------- graph boundaries (batch is sorted) ----------------
__global__ void bounds_kernel(const int* __restrict__ batch, int* __restrict__ gs) {
    int n = blockIdx.x * 256 + threadIdx.x;
    if (n >= N_NODES) return;
    int bcur = batch[n];
    int prev = (n == 0) ? -1 : batch[n - 1];
    for (int g = prev + 1; g <= bcur; g++) gs[g] = n;
    if (n == N_NODES - 1) {
        for (int g = bcur + 1; g <= N_GRAPHS; g++) gs[g] = N_NODES;
    }
}

// ---------------- sum pool: orig-node order (batch sorted), bf16 h rows via inv ----------------
__global__ __launch_bounds__(256) void pool_kernel(const unsigned int* __restrict__ hbf,
                                                   const int* __restrict__ inv,
                                                   const int* __restrict__ batch,
                                                   float* __restrict__ sums) {
    int wave = threadIdx.x >> 6, l = threadIdx.x & 63;
    int nbase = (blockIdx.x * 4 + wave) * 8;
    float a0 = 0.f, a1 = 0.f;
    int g = -1;
#pragma unroll
    for (int i = 0; i < 8; i++) {
        int n = nbase + i;
        if (n >= N_NODES) break;
        int bg = batch[n];
        if (bg != g) {
            if (g >= 0) {
                atomicAdd(&sums[g * 128 + 2 * l], a0);
                atomicAdd(&sums[g * 128 + 2 * l + 1], a1);
            }
            g = bg; a0 = 0.f; a1 = 0.f;
        }
        int p = inv[n];  // wave-uniform
        unsigned int hv = hbf[(size_t)p * 64 + l];
        a0 += bflo(hv); a1 += bfhi(hv);
    }
    if (g >= 0) {
        atomicAdd(&sums[g * 128 + 2 * l], a0);
        atomicAdd(&sums[g * 128 + 2 * l + 1], a1);
    }
}

// ---------------- MLP head (divides pooled sums by count inline) ----------------
__global__ __launch_bounds__(512) void mlp_kernel(const float* __restrict__ sums,
                                                  const int* __restrict__ gs,
                                                  const float* __restrict__ Wh1,
                                                  const float* __restrict__ bh1,
                                                  const float* __restrict__ Wh2,
                                                  const float* __restrict__ bh2,
                                                  float* __restrict__ out) {
    int g = blockIdx.x;
    __shared__ float pl[128];
    __shared__ float red[8];
    int tid = threadIdx.x;
    if (tid < 128) {
        float cnt = fmaxf((float)(gs[g + 1] - gs[g]), 1.0f);
        pl[tid] = sums[g * 128 + tid] / cnt;
    }
    __syncthreads();
    float s = bh1[tid];
#pragma unroll 16
    for (int k = 0; k < 128; k++) s = fmaf(pl[k], Wh1[k * 512 + tid], s);
    float gl = 0.5f * s * (1.0f + erff(s * 0.70710678118654752f));
    float p = gl * Wh2[tid];
    for (int off = 32; off >= 1; off >>= 1) p += __shfl_down(p, off);
    if ((tid & 63) == 0) red[tid >> 6] = p;
    __syncthreads();
    if (tid == 0) {
        float tot = 0.f;
        for (int i = 0; i < 8; i++) tot += red[i];
        out[g] = tot + bh2[0];
    }
}

extern "C" void kernel_launch(void* const* d_in, const int* in_sizes, int n_in,
                              void* d_out, int out_size, void* d_ws, size_t ws_size,
                              hipStream_t stream) {
    const float* x = (const float*)d_in[0];
    const int* ei = (const int*)d_in[1];
    const float* eattr = (const float*)d_in[2];
    const int* batch = (const int*)d_in[3];
    const float* Wv = (const float*)d_in[4];
    const float* We = (const float*)d_in[5];
    const float* convW = (const float*)d_in[6];
    const float* convB = (const float*)d_in[7];
    const float* Wh1 = (const float*)d_in[8];
    const float* bh1 = (const float*)d_in[9];
    const float* Wh2 = (const float*)d_in[10];
    const float* bh2 = (const float*)d_in[11];
    float* out = (float*)d_out;

    const int* src = ei;
    const int* dst = ei + N_EDGES;

    // workspace carve-up (256B aligned)
    char* w = (char*)d_ws;
    size_t off = 0;
    auto alloc = [&](size_t bytes) -> char* {
        char* p = w + off;
        off += (bytes + 255) & ~(size_t)255;
        return p;
    };
    unsigned int* hbfA = (unsigned int*)alloc((size_t)N_NODES * 64 * 4);  // bf16 h ping
    unsigned int* hbfB = (unsigned int*)alloc((size_t)N_NODES * 64 * 4);  // bf16 h pong
    uint4* wb = (uint4*)alloc((size_t)N_LAYERS * 32 * 64 * 16);           // MFMA W frags
    int* deg = (int*)alloc((size_t)(N_NODES + 1) * 4);
    int* rowp = (int*)alloc((size_t)(N_NODES + 1) * 4);
    int* cursor = (int*)alloc((size_t)(N_NODES + 1) * 4);
    int* csum = (int*)alloc((size_t)NCHUNK * 4);
    int* coff = (int*)alloc((size_t)NCHUNK * 4);
    int* bhist = (int*)alloc((size_t)NCHUNK * 64 * 4);
    int* boff = (int*)alloc((size_t)NCHUNK * 64 * 4);
    int* nperm = (int*)alloc((size_t)N_NODES * 4);
    int* inv = (int*)alloc((size_t)N_NODES * 4);
    unsigned short* dstinv16 = (unsigned short*)alloc((size_t)N_EDGES * 2);
    uint4* erec = (uint4*)alloc((size_t)N_EDGES * 16);
    int* gs = (int*)alloc((size_t)(N_GRAPHS + 1) * 4);
    float* sums = (float*)alloc((size_t)N_GRAPHS * DCH * 4);
    (void)ws_size; (void)n_in; (void)in_sizes; (void)out_size;

    hipMemsetAsync(deg, 0, (size_t)(N_NODES + 1) * 4, stream);
    hipMemsetAsync(sums, 0, (size_t)N_GRAPHS * DCH * 4, stream);

    hist_kernel<<<N_EDGES / 256, 256, 0, stream>>>(dst, deg);
    dsort_hist_kernel<<<NCHUNK, 256, 0, stream>>>(deg, bhist);
    dsort_scan_kernel<<<1, 64, 0, stream>>>(bhist, boff);
    dsort_scatter_kernel<<<NCHUNK, 256, 0, stream>>>(deg, boff, nperm, inv);
    dstinv_kernel<<<N_EDGES / 256, 256, 0, stream>>>(dst, inv, dstinv16);
    chunksum_kernel<<<NCHUNK, 256, 0, stream>>>(deg, nperm, csum);
    chunkscan_kernel<<<1, 256, 0, stream>>>(csum, coff);
    applyscan_kernel<<<NCHUNK, 256, 0, stream>>>(deg, nperm, coff, rowp, cursor);
    scatter_kernel<<<782 * NSLICE, 256, 0, stream>>>(src, dstinv16, inv, eattr, cursor, erec);
    wconv_kernel<<<72, 256, 0, stream>>>(convW, wb);
    h0_kernel<<<N_NODES * 64 / 256, 256, 0, stream>>>(x, Wv, inv, hbfA);
    bounds_kernel<<<(N_NODES + 255) / 256, 256, 0, stream>>>(batch, gs);

    unsigned int* bfcur = hbfA;
    unsigned int* bfnext = hbfB;
    for (int layer = 0; layer < N_LAYERS; layer++) {
        layer_kernel<<<N_NODES / 16, 256, 0, stream>>>(
            bfcur, erec, rowp, We,
            (const short8*)(wb + (size_t)layer * 2048), convB + (size_t)layer * DCH,
            bfnext);
        unsigned int* tb = bfcur; bfcur = bfnext; bfnext = tb;
    }

    pool_kernel<<<(N_NODES + 31) / 32, 256, 0, stream>>>(bfcur, inv, batch, sums);
    mlp_kernel<<<N_GRAPHS, 512, 0, stream>>>(sums, gs, Wh1, bh1, Wh2, bh2, out);
}